// Round 1
// baseline (55.710 us; speedup 1.0000x reference)
//
#include <hip/hip_runtime.h>
#include <math.h>

#define S_    10
#define N_    2
#define C_    48
#define HWD   64
#define M_    512
#define PADK  4
#define PAIRS 20           // S_*N_
#define PITCH2 10240       // PAIRS*M_  (transposed ws pitch)
#define YPITCH 516         // LDS pitch for y chunk (mult of 4, odd*4 bank step)

// ws layout (float offsets)
#define OFF_MU 0
#define OFF_XH 480
#define OFF_YH (480 + 491520)
#define OFF_CM (480 + 2*491520)

__device__ __forceinline__ int gidx(int n, int c, int h, int w, int d) {
  return (((n * C_ + c) * HWD + h) * HWD + w) * HWD + d;
}

// ---------------- kernel A: per-(s,c) mean of y over N x M ----------------
__global__ void k_mu(const float* __restrict__ y, const int* __restrict__ hi,
                     const int* __restrict__ wi, const int* __restrict__ di,
                     float* __restrict__ mu) {
  int b = blockIdx.x;            // s*48 + c
  int s = b / C_, c = b % C_;
  int h0 = hi[s] - PADK, w0 = wi[s] - PADK, d0 = di[s] - PADK;
  int t = threadIdx.x;           // 64 threads
  float sum = 0.f;
#pragma unroll
  for (int j = 0; j < 16; ++j) {
    int i = t + 64 * j;          // 0..1023 over (n,m)
    int n = i >> 9, m = i & 511;
    int mh = m >> 6, mw = (m >> 3) & 7, md = m & 7;
    sum += y[gidx(n, c, h0 + mh, w0 + mw, d0 + md)];
  }
#pragma unroll
  for (int off = 32; off; off >>= 1) sum += __shfl_xor(sum, off);
  if (t == 0) mu[b] = sum * (1.0f / 1024.0f);
}

// ------------- kernel B: gather, center, L2-normalize, store [c][col] -----
__global__ void k_norm(const float* __restrict__ x, const float* __restrict__ y,
                       const int* __restrict__ hi, const int* __restrict__ wi,
                       const int* __restrict__ di, const float* __restrict__ mu,
                       float* __restrict__ ws) {
  int b = blockIdx.x;            // which*40 + s*4 + n*2 + half
  int which = b / 40;
  int rem = b % 40;
  int s = rem >> 2;
  int n = (rem >> 1) & 1;
  int half = rem & 1;
  int m = half * 256 + threadIdx.x;
  int h0 = hi[s] - PADK, w0 = wi[s] - PADK, d0 = di[s] - PADK;
  int mh = m >> 6, mw = (m >> 3) & 7, md = m & 7;
  const float* src = which ? y : x;
  float* dst = ws + (which ? OFF_YH : OFF_XH);
  const float* muS = mu + s * C_;
  int base = gidx(n, 0, h0 + mh, w0 + mw, d0 + md);
  float v[C_];
  float ss = 0.f;
#pragma unroll
  for (int c = 0; c < C_; ++c) {
    v[c] = src[base + c * (HWD * HWD * HWD)] - muS[c];
    ss += v[c] * v[c];
  }
  float sc = 1.0f / fmaxf(sqrtf(ss), 1e-12f);
  int pair = s * 2 + n;
  float* out = dst + pair * M_ + m;
#pragma unroll
  for (int c = 0; c < C_; ++c) out[c * PITCH2] = v[c] * sc;
}

// ------------- kernel C: dist + row-softmax + column-max (atomic) ---------
__global__ __launch_bounds__(256, 2) void k_main(const float* __restrict__ xh,
                                                 const float* __restrict__ yh,
                                                 float* __restrict__ colmax) {
  int b = blockIdx.x;            // pair*8 + tile
  int pair = b >> 3;
  int tile = b & 7;
  int t = threadIdx.x;
  int lane = t & 63, wv = t >> 6;

  __shared__ float xl[48 * 64];        // x tile: [c][row]  (64 rows)
  __shared__ float yl[12 * YPITCH];    // y chunk: [c_rel][p] pitch 516

  // stage x tile (48 c-rows of 64 contiguous floats)
  const float* xsrc = xh + pair * M_ + tile * 64;
#pragma unroll
  for (int i = 0; i < 3; ++i) {
    int li = t + 256 * i;              // 0..767 float4s
    int c = li >> 4, r4 = (li & 15) << 2;
    float4 vv = *(const float4*)(xsrc + c * PITCH2 + r4);
    *(float4*)(xl + c * 64 + r4) = vv;
  }

  float acc[16][8];
#pragma unroll
  for (int r = 0; r < 16; ++r)
#pragma unroll
    for (int k = 0; k < 8; ++k) acc[r][k] = 0.f;

  const float* ysrc = yh + pair * M_;
  for (int chunk = 0; chunk < 4; ++chunk) {
    __syncthreads();
    // stage 12 channels of y: [c_rel][0..511], fully coalesced
#pragma unroll
    for (int i = 0; i < 6; ++i) {
      int li = t + 256 * i;            // 0..1535 float4s
      int cr = li >> 7, p4 = (li & 127) << 2;
      float4 vv = *(const float4*)(ysrc + (chunk * 12 + cr) * PITCH2 + p4);
      *(float4*)(yl + cr * YPITCH + p4) = vv;
    }
    __syncthreads();
#pragma unroll
    for (int cr = 0; cr < 12; ++cr) {
      float yv[8];
#pragma unroll
      for (int k = 0; k < 8; ++k) yv[k] = yl[cr * YPITCH + lane + 64 * k];
      int c = chunk * 12 + cr;
#pragma unroll
      for (int r4 = 0; r4 < 4; ++r4) {
        float4 xv = *(const float4*)(xl + c * 64 + wv * 16 + r4 * 4);
        float xs0 = xv.x, xs1 = xv.y, xs2 = xv.z, xs3 = xv.w;
#pragma unroll
        for (int k = 0; k < 8; ++k) {
          acc[r4 * 4 + 0][k] += xs0 * yv[k];
          acc[r4 * 4 + 1][k] += xs1 * yv[k];
          acc[r4 * 4 + 2][k] += xs2 * yv[k];
          acc[r4 * 4 + 3][k] += xs3 * yv[k];
        }
      }
    }
  }

  // epilogue: per row min -> softmax over p -> accumulate column max
  float cmax[8];
#pragma unroll
  for (int k = 0; k < 8; ++k) cmax[k] = 0.f;

#pragma unroll
  for (int r = 0; r < 16; ++r) {
    float dmin = 3.4e38f;
#pragma unroll
    for (int k = 0; k < 8; ++k) {
      float d = 1.0f - acc[r][k];
      acc[r][k] = d;
      dmin = fminf(dmin, d);
    }
#pragma unroll
    for (int off = 32; off; off >>= 1) dmin = fminf(dmin, __shfl_xor(dmin, off));
    float inv = 2.0f / (dmin + 1e-5f);   // w = 2*(1 - d/(dmin+eps)); max w < 2, no overflow
    float e[8], sm = 0.f;
#pragma unroll
    for (int k = 0; k < 8; ++k) {
      e[k] = __expf(2.0f - acc[r][k] * inv);
      sm += e[k];
    }
#pragma unroll
    for (int off = 32; off; off >>= 1) sm += __shfl_xor(sm, off);
    float rs = 1.0f / sm;
#pragma unroll
    for (int k = 0; k < 8; ++k) cmax[k] = fmaxf(cmax[k], e[k] * rs);
  }
  // positive floats: uint compare == float compare
#pragma unroll
  for (int k = 0; k < 8; ++k)
    atomicMax((unsigned int*)&colmax[pair * M_ + lane + 64 * k],
              __float_as_uint(cmax[k]));
}

// ------------- kernel D: mean over p, -log, average -> scalar -------------
__global__ void k_final(const float* __restrict__ colmax, float* __restrict__ out) {
  int t = threadIdx.x;           // 512 threads
  int lane = t & 63, wv = t >> 6;
  __shared__ float red[8];
  float total = 0.f;
  for (int pair = 0; pair < PAIRS; ++pair) {
    float v = colmax[pair * M_ + t];
#pragma unroll
    for (int off = 32; off; off >>= 1) v += __shfl_xor(v, off);
    if (lane == 0) red[wv] = v;
    __syncthreads();
    if (t == 0) {
      float sm = 0.f;
#pragma unroll
      for (int i = 0; i < 8; ++i) sm += red[i];
      total += -logf(sm * (1.0f / 512.0f) + 1e-5f);
    }
    __syncthreads();
  }
  if (t == 0) out[0] = total * (1.0f / (float)PAIRS);
}

extern "C" void kernel_launch(void* const* d_in, const int* in_sizes, int n_in,
                              void* d_out, int out_size, void* d_ws, size_t ws_size,
                              hipStream_t stream) {
  const float* x = (const float*)d_in[0];
  const float* y = (const float*)d_in[1];
  const int* hi = (const int*)d_in[2];
  const int* wi = (const int*)d_in[3];
  const int* di = (const int*)d_in[4];
  float* ws = (float*)d_ws;
  float* out = (float*)d_out;

  // zero the column-max accumulator (0.0f == 0 bits)
  hipMemsetAsync(ws + OFF_CM, 0, PAIRS * M_ * sizeof(float), stream);
  k_mu<<<S_ * C_, 64, 0, stream>>>(y, hi, wi, di, ws + OFF_MU);
  k_norm<<<80, 256, 0, stream>>>(x, y, hi, wi, di, ws + OFF_MU, ws);
  k_main<<<PAIRS * 8, 256, 0, stream>>>(ws + OFF_XH, ws + OFF_YH, ws + OFF_CM);
  k_final<<<1, 512, 0, stream>>>(ws + OFF_CM, out);
}